// Round 4
// baseline (971.516 us; speedup 1.0000x reference)
//
#include <hip/hip_runtime.h>
#include <stdint.h>

#define BB 2
#define NN 4160
#define CC 512
#define HIDD 2048
#define HH 4096
#define QSCALE 0.12751742f   // log2(e)/sqrt(128), folded into Q epilogue

typedef short bf16x8 __attribute__((ext_vector_type(8)));
typedef float f32x4 __attribute__((ext_vector_type(4)));

__device__ __forceinline__ float bf2f(ushort u){
  union { uint32_t u32; float f; } c; c.u32 = ((uint32_t)u) << 16; return c.f;
}
__device__ __forceinline__ ushort f2bf(float f){
  union { float f; uint32_t u32; } c; c.f = f;
  uint32_t r = c.u32 + 0x7fffu + ((c.u32 >> 16) & 1u);
  return (ushort)(r >> 16);
}
__device__ __forceinline__ float gelu_f(float x){
  return 0.5f * x * (1.0f + erff(x * 0.70710678118654752440f));
}

template<int MODE>
__device__ __forceinline__ int rowmap(int m){
  if (MODE == 0) return m;                              // identity
  if (MODE == 1) return (m >> 12) * NN + (m & 4095);    // seq rows (H=4096)
  return (m >> 6) * NN + HH + (m & 63);                 // sem rows (64/batch)
}

// ---------------- weights fp32 -> bf16 (one contiguous bf16 arena) ----------------
__global__ __launch_bounds__(256) void wconv_kernel(
    const float* __restrict__ s0, const float* __restrict__ s1,
    const float* __restrict__ s2, const float* __restrict__ s3,
    const float* __restrict__ s4, const float* __restrict__ s5,
    const float* __restrict__ s6, ushort* __restrict__ dst)
{
  int i4 = (blockIdx.x * 256 + threadIdx.x) * 4;
  const float* s; int off;
  if      (i4 <  262144){ s = s0; off = 0;       }
  else if (i4 <  786432){ s = s1; off = 262144;  }
  else if (i4 < 1048576){ s = s2; off = 786432;  }
  else if (i4 < 2097152){ s = s3; off = 1048576; }
  else if (i4 < 3145728){ s = s4; off = 2097152; }
  else if (i4 < 3670016){ s = s5; off = 3145728; }
  else                  { s = s6; off = 3670016; }
  float4 v = *(const float4*)(s + (i4 - off));
  union { ushort h[4]; uint2 u; } o;
  o.h[0] = f2bf(v.x); o.h[1] = f2bf(v.y); o.h[2] = f2bf(v.z); o.h[3] = f2bf(v.w);
  *(uint2*)(dst + i4) = o.u;
}

// ---------------- LayerNorm over C=512, one wave per row, bf16 out ----------------
__global__ __launch_bounds__(256) void ln_kernel(
    const float* __restrict__ x, const float* __restrict__ w,
    const float* __restrict__ b, ushort* __restrict__ out)
{
  int row  = blockIdx.x * 4 + (threadIdx.x >> 6);
  int lane = threadIdx.x & 63;
  const float4* xr = (const float4*)(x + (size_t)row * CC);
  float4 v0 = xr[lane];
  float4 v1 = xr[lane + 64];
  float s  = v0.x + v0.y + v0.z + v0.w + v1.x + v1.y + v1.z + v1.w;
  float ss = v0.x*v0.x + v0.y*v0.y + v0.z*v0.z + v0.w*v0.w
           + v1.x*v1.x + v1.y*v1.y + v1.z*v1.z + v1.w*v1.w;
  #pragma unroll
  for (int off = 1; off < 64; off <<= 1){
    s  += __shfl_xor(s, off);
    ss += __shfl_xor(ss, off);
  }
  float mu  = s * (1.0f / CC);
  float var = ss * (1.0f / CC) - mu * mu;
  float rs  = rsqrtf(var + 1e-5f);
  const float4* wp = (const float4*)w;
  const float4* bp = (const float4*)b;
  float4 w0 = wp[lane], w1 = wp[lane + 64], b0 = bp[lane], b1 = bp[lane + 64];
  union { ushort h[4]; uint2 u; } o0, o1;
  o0.h[0] = f2bf((v0.x - mu) * rs * w0.x + b0.x);
  o0.h[1] = f2bf((v0.y - mu) * rs * w0.y + b0.y);
  o0.h[2] = f2bf((v0.z - mu) * rs * w0.z + b0.z);
  o0.h[3] = f2bf((v0.w - mu) * rs * w0.w + b0.w);
  o1.h[0] = f2bf((v1.x - mu) * rs * w1.x + b1.x);
  o1.h[1] = f2bf((v1.y - mu) * rs * w1.y + b1.y);
  o1.h[2] = f2bf((v1.z - mu) * rs * w1.z + b1.z);
  o1.h[3] = f2bf((v1.w - mu) * rs * w1.w + b1.w);
  ushort* orow = out + (size_t)row * CC;
  ((uint2*)orow)[lane]      = o0.u;
  ((uint2*)orow)[lane + 64] = o1.u;
}

// ---------------- GEMM: out = A(MxK) @ W(OxK)^T + bias; BM=128, BK=64 ------------
// Register-prefetch pipeline: next K-tile loaded into regs while current tile
// computes (regular global loads: L2-cached, no vmcnt drain at barriers).
// LDS layout [row][chunk^(row&7)]: conflict-free ds_read_b128 fragments.
// EPI 0: bf16 store   EPI 1: bf16(gelu)   EPI 2: outf = resid + gamma*(acc+bias)
// EPI 3: fused QKV: col<512 -> qb*QSCALE; col<1024 -> kb; else -> vt transposed
template<int BN, int AMAP, int OMAP, int EPI>
__global__ __launch_bounds__(256) void gemm_kernel(
    const ushort* __restrict__ A, int lda,
    const ushort* __restrict__ W,
    const float* __restrict__ bias, const float* __restrict__ bias2,
    ushort* __restrict__ outb, ushort* __restrict__ outb2,
    float* __restrict__ outf,
    const float* __restrict__ resid, const float* __restrict__ gamma,
    ushort* __restrict__ vt, int K, int O)
{
  constexpr int NCT = BN / 32;           // col 16-tiles per wave
  constexpr int NW  = BN / 32;           // W reg-chunks (BN*8/256)
  __shared__ __align__(16) ushort As[128 * 64];
  __shared__ __align__(16) ushort Ws[BN * 64];
  int tid  = threadIdx.x;
  int lane = tid & 63;
  int wv   = tid >> 6;
  int w0   = wv & 1, w1 = wv >> 1;
  int quad = lane >> 4, l16 = lane & 15;
  int m0 = blockIdx.x * 128;
  int o0 = blockIdx.y * BN;

  f32x4 acc[4][NCT];
  f32x4 zf = {0.f, 0.f, 0.f, 0.f};
  #pragma unroll
  for (int i = 0; i < 4; i++)
    #pragma unroll
    for (int j = 0; j < NCT; j++) acc[i][j] = zf;

  uint4 areg[4], wreg[NW];
  // prologue: first K-tile into registers
  #pragma unroll
  for (int i = 0; i < 4; i++){
    int o = i * 256 + tid;
    int row = o >> 3, c = (o & 7) ^ (row & 7);
    areg[i] = *(const uint4*)(A + (size_t)rowmap<AMAP>(m0 + row) * lda + c * 8);
  }
  #pragma unroll
  for (int i = 0; i < NW; i++){
    int o = i * 256 + tid;
    int row = o >> 3, c = (o & 7) ^ (row & 7);
    wreg[i] = *(const uint4*)(W + (size_t)(o0 + row) * K + c * 8);
  }

  for (int k0 = 0; k0 < K; k0 += 64){
    __syncthreads();   // previous tile's ds_reads done before overwrite
    #pragma unroll
    for (int i = 0; i < 4; i++) *(uint4*)&As[(i * 256 + tid) * 8] = areg[i];
    #pragma unroll
    for (int i = 0; i < NW; i++) *(uint4*)&Ws[(i * 256 + tid) * 8] = wreg[i];
    if (k0 + 64 < K){   // issue next tile's loads; in flight across compute
      #pragma unroll
      for (int i = 0; i < 4; i++){
        int o = i * 256 + tid;
        int row = o >> 3, c = (o & 7) ^ (row & 7);
        areg[i] = *(const uint4*)(A + (size_t)rowmap<AMAP>(m0 + row) * lda + k0 + 64 + c * 8);
      }
      #pragma unroll
      for (int i = 0; i < NW; i++){
        int o = i * 256 + tid;
        int row = o >> 3, c = (o & 7) ^ (row & 7);
        wreg[i] = *(const uint4*)(W + (size_t)(o0 + row) * K + k0 + 64 + c * 8);
      }
    }
    __syncthreads();   // staged tile visible
    #pragma unroll
    for (int kk = 0; kk < 2; kk++){
      bf16x8 af[4], bfr[NCT];
      #pragma unroll
      for (int rt = 0; rt < 4; rt++){
        int row = w1 * 64 + rt * 16 + l16;
        af[rt] = *(const bf16x8*)&As[(row * 8 + ((kk * 4 + quad) ^ (row & 7))) * 8];
      }
      #pragma unroll
      for (int ct = 0; ct < NCT; ct++){
        int row = w0 * (BN / 2) + ct * 16 + l16;
        bfr[ct] = *(const bf16x8*)&Ws[(row * 8 + ((kk * 4 + quad) ^ (row & 7))) * 8];
      }
      #pragma unroll
      for (int rt = 0; rt < 4; rt++)
        #pragma unroll
        for (int ct = 0; ct < NCT; ct++)
          acc[rt][ct] = __builtin_amdgcn_mfma_f32_16x16x32_bf16(af[rt], bfr[ct], acc[rt][ct], 0, 0, 0);
    }
  }

  #pragma unroll
  for (int ct = 0; ct < NCT; ct++){
    int col = o0 + w0 * (BN / 2) + ct * 16 + l16;
    #pragma unroll
    for (int rt = 0; rt < 4; rt++){
      int mb = m0 + w1 * 64 + rt * 16 + quad * 4;
      if (EPI == 3){
        if (col < 512){
          float bs = bias[col];
          #pragma unroll
          for (int r = 0; r < 4; r++)
            outb[(size_t)(mb + r) * 512 + col] = f2bf((acc[rt][ct][r] + bs) * QSCALE);
        } else if (col < 1024){
          float bs = bias2[col - 512];
          #pragma unroll
          for (int r = 0; r < 4; r++)
            outb2[(size_t)(mb + r) * 512 + (col - 512)] = f2bf(acc[rt][ct][r] + bs);
        } else {
          float bs = bias2[col - 512];
          int dd = col - 1024;
          int h2 = dd >> 7, d = dd & 127;
          int bbat = (mb >= NN) ? 1 : 0;
          int n = mb - bbat * NN;
          union { ushort h[4]; uint2 u; } pk;
          #pragma unroll
          for (int r = 0; r < 4; r++) pk.h[r] = f2bf(acc[rt][ct][r] + bs);
          *(uint2*)&vt[((size_t)((bbat * 4 + h2) * 128 + d)) * NN + n] = pk.u;
        }
      } else {
        float bs = bias[col];
        #pragma unroll
        for (int r = 0; r < 4; r++){
          float v = acc[rt][ct][r] + bs;
          if (EPI == 1) v = gelu_f(v);
          if (EPI == 0 || EPI == 1){
            outb[(size_t)rowmap<OMAP>(mb + r) * O + col] = f2bf(v);
          } else {
            size_t off = (size_t)rowmap<OMAP>(mb + r) * O + col;
            outf[off] = resid[off] + gamma[col] * v;
          }
        }
      }
    }
  }
}

// ---------------- flash attention, split-K, BARRIER-FREE --------------------------
// Q tile 128 (4 waves x 32 rows), key tile 64, 3 key-splits. Q pre-scaled by
// log2(e)/sqrt(d) -> exp2-domain softmax. K and V^T B-fragments are loaded
// DIRECTLY from global (both layouts give 16 B/lane contiguous reads; L1/L2
// absorb the intra-block redundancy). Only P round-trips through wave-private
// LDS. No __syncthreads anywhere -> waves free-run, pipes overlap.
__global__ __launch_bounds__(256, 3) void attn_kernel(
    const ushort* __restrict__ q, const ushort* __restrict__ kbuf,
    const ushort* __restrict__ vt, ushort* __restrict__ opart, float* __restrict__ ml)
{
  __shared__ __align__(16) ushort Ps[128 * 64];    // [row][col ^ quad*16], wave-private rows
  int tid = threadIdx.x, lane = tid & 63, wv = tid >> 6;
  int quad = lane >> 4, l16 = lane & 15;
  int qt = blockIdx.x, bh = blockIdx.y, ks = blockIdx.z;
  int b = bh >> 2, h = bh & 3;
  int jt0 = ks * 22;
  int jt1 = (ks == 2) ? 65 : jt0 + 22;

  // Q fragments straight from global (A-layout: lane=row, quad=k-chunk)
  bf16x8 qf[2][4];
  #pragma unroll
  for (int rt = 0; rt < 2; rt++)
    #pragma unroll
    for (int kb = 0; kb < 4; kb++){
      int qr = qt * 128 + wv * 32 + rt * 16 + l16;
      qr = (qr < NN) ? qr : (NN - 1);
      qf[rt][kb] = *(const bf16x8*)(q + ((size_t)(b * NN + qr)) * CC + h * 128 + kb * 32 + quad * 8);
    }

  float mrow[2][4], lrow[2][4];
  #pragma unroll
  for (int rt = 0; rt < 2; rt++)
    #pragma unroll
    for (int r = 0; r < 4; r++){ mrow[rt][r] = -1e30f; lrow[rt][r] = 0.f; }
  f32x4 oa[2][8];
  f32x4 zf = {0.f, 0.f, 0.f, 0.f};
  #pragma unroll
  for (int rt = 0; rt < 2; rt++)
    #pragma unroll
    for (int nb = 0; nb < 8; nb++) oa[rt][nb] = zf;

  const ushort* kg0 = kbuf + ((size_t)b * NN) * CC + h * 128;
  const ushort* vg0 = vt + ((size_t)bh * 128) * NN;

  for (int jt = jt0; jt < jt1; jt++){
    const ushort* kbase = kg0 + (size_t)(jt * 64) * CC;
    const ushort* vbase = vg0 + jt * 64;

    // S = Q K^T : K B-frags direct from global (lane=key, quad=k-chunk)
    f32x4 s[2][4];
    #pragma unroll
    for (int rt = 0; rt < 2; rt++)
      #pragma unroll
      for (int ct = 0; ct < 4; ct++) s[rt][ct] = zf;
    #pragma unroll
    for (int ct = 0; ct < 4; ct++){
      bf16x8 kf[4];
      #pragma unroll
      for (int kb = 0; kb < 4; kb++)
        kf[kb] = *(const bf16x8*)(kbase + (size_t)(ct * 16 + l16) * CC + kb * 32 + quad * 8);
      #pragma unroll
      for (int kb = 0; kb < 4; kb++)
        #pragma unroll
        for (int rt = 0; rt < 2; rt++)
          s[rt][ct] = __builtin_amdgcn_mfma_f32_16x16x32_bf16(qf[rt][kb], kf[kb], s[rt][ct], 0, 0, 0);
    }

    // online softmax (exp2 domain), rows quad*4+r per rt
    #pragma unroll
    for (int rt = 0; rt < 2; rt++){
      #pragma unroll
      for (int r = 0; r < 4; r++){
        float mx = fmaxf(fmaxf(s[rt][0][r], s[rt][1][r]), fmaxf(s[rt][2][r], s[rt][3][r]));
        #pragma unroll
        for (int off = 1; off < 16; off <<= 1) mx = fmaxf(mx, __shfl_xor(mx, off));
        float mn = fmaxf(mrow[rt][r], mx);
        float al = __builtin_amdgcn_exp2f(mrow[rt][r] - mn);
        mrow[rt][r] = mn;
        #pragma unroll
        for (int ct = 0; ct < 4; ct++) s[rt][ct][r] = __builtin_amdgcn_exp2f(s[rt][ct][r] - mn);
        float t = s[rt][0][r] + s[rt][1][r] + s[rt][2][r] + s[rt][3][r];
        #pragma unroll
        for (int off = 1; off < 16; off <<= 1) t += __shfl_xor(t, off);
        lrow[rt][r] = lrow[rt][r] * al + t;
        #pragma unroll
        for (int nb = 0; nb < 8; nb++) oa[rt][nb][r] *= al;
      }
      // P: C-layout -> LDS (swizzled by quad), wave-private rows (no barrier)
      #pragma unroll
      for (int ct = 0; ct < 4; ct++)
        #pragma unroll
        for (int r = 0; r < 4; r++)
          Ps[(wv * 32 + rt * 16 + quad * 4 + r) * 64 + ((ct * 16 + l16) ^ (quad * 16))] = f2bf(s[rt][ct][r]);
    }

    // O += P V : P A-frags from LDS, V^T B-frags direct from global
    bf16x8 pf[2][2];
    #pragma unroll
    for (int rt = 0; rt < 2; rt++)
      #pragma unroll
      for (int kb2 = 0; kb2 < 2; kb2++){
        int rowA = wv * 32 + rt * 16 + l16;
        pf[rt][kb2] = *(const bf16x8*)&Ps[rowA * 64 + ((kb2 * 32 + quad * 8) ^ (((l16 >> 2) & 3) * 16))];
      }
    #pragma unroll
    for (int nb = 0; nb < 8; nb++){
      bf16x8 vf[2];
      #pragma unroll
      for (int kb2 = 0; kb2 < 2; kb2++)
        vf[kb2] = *(const bf16x8*)(vbase + (size_t)(nb * 16 + l16) * NN + kb2 * 32 + quad * 8);
      #pragma unroll
      for (int kb2 = 0; kb2 < 2; kb2++)
        #pragma unroll
        for (int rt = 0; rt < 2; rt++)
          oa[rt][nb] = __builtin_amdgcn_mfma_f32_16x16x32_bf16(pf[rt][kb2], vf[kb2], oa[rt][nb], 0, 0, 0);
    }
  }

  // bf16 partials, fully coalesced (512 B per store instruction):
  // element (row,col) row=wv*32+rt*16+quad*4+r, col=nb*16+l16
  //   -> opart[part*16384 + ((wv*2+rt)*8+nb)*256 + lane*4 + r]
  int part = (qt * 8 + bh) * 3 + ks;
  ushort* op = opart + (size_t)part * 16384;
  #pragma unroll
  for (int rt = 0; rt < 2; rt++)
    #pragma unroll
    for (int nb = 0; nb < 8; nb++){
      union { ushort h[4]; uint2 u; } pk;
      #pragma unroll
      for (int r = 0; r < 4; r++) pk.h[r] = f2bf(oa[rt][nb][r]);
      *(uint2*)&op[(((wv * 2 + rt) * 8 + nb) * 64 + lane) * 4] = pk.u;
    }
  if (l16 == 0){
    #pragma unroll
    for (int rt = 0; rt < 2; rt++)
      #pragma unroll
      for (int r = 0; r < 4; r++){
        int row = wv * 32 + rt * 16 + quad * 4 + r;
        ml[(size_t)part * 256 + row]       = mrow[rt][r];
        ml[(size_t)part * 256 + 128 + row] = lrow[rt][r];
      }
  }
}

// ---------------- combine 3 key-split bf16 partials -> bf16 attention out --------
__global__ __launch_bounds__(256) void attn_combine_kernel(
    const ushort* __restrict__ opart, const float* __restrict__ ml,
    ushort* __restrict__ out)
{
  int qt = blockIdx.x, bh = blockIdx.y;
  int b = bh >> 2, h = bh & 3;
  int tid = threadIdx.x;
  int lane = tid & 63, quad = lane >> 4, l16 = lane & 15;
  int base = (qt * 8 + bh) * 3;
  const ushort* p0 = opart + (size_t)(base + 0) * 16384;
  const ushort* p1 = opart + (size_t)(base + 1) * 16384;
  const ushort* p2 = opart + (size_t)(base + 2) * 16384;

  #pragma unroll
  for (int pass = 0; pass < 2; pass++){
    int wvrt = (tid >> 6) * 2 + pass;           // (wv*2+rt) in [0,8)
    int wv = wvrt >> 1, rt = wvrt & 1;
    float w0r[4], w1r[4], w2r[4], invr[4];
    int rows[4];
    #pragma unroll
    for (int r = 0; r < 4; r++){
      int row = wv * 32 + rt * 16 + quad * 4 + r;
      rows[r] = row;
      float m0 = ml[(size_t)(base + 0) * 256 + row];
      float m1 = ml[(size_t)(base + 1) * 256 + row];
      float m2 = ml[(size_t)(base + 2) * 256 + row];
      float l0 = ml[(size_t)(base + 0) * 256 + 128 + row];
      float l1 = ml[(size_t)(base + 1) * 256 + 128 + row];
      float l2 = ml[(size_t)(base + 2) * 256 + 128 + row];
      float mx = fmaxf(fmaxf(m0, m1), m2);
      w0r[r] = __builtin_amdgcn_exp2f(m0 - mx);
      w1r[r] = __builtin_amdgcn_exp2f(m1 - mx);
      w2r[r] = __builtin_amdgcn_exp2f(m2 - mx);
      invr[r] = 1.0f / (w0r[r] * l0 + w1r[r] * l1 + w2r[r] * l2);
    }
    #pragma unroll
    for (int nb = 0; nb < 8; nb++){
      int idx = ((wvrt * 8 + nb) * 64 + lane) * 4;
      union { ushort h[4]; uint2 u; } a, c, d;
      a.u = *(const uint2*)&p0[idx];
      c.u = *(const uint2*)&p1[idx];
      d.u = *(const uint2*)&p2[idx];
      #pragma unroll
      for (int r = 0; r < 4; r++){
        int n = qt * 128 + rows[r];
        if (n < NN){
          float v = (w0r[r] * bf2f(a.h[r]) + w1r[r] * bf2f(c.h[r]) + w2r[r] * bf2f(d.h[r])) * invr[r];
          out[((size_t)(b * NN + n)) * CC + h * 128 + nb * 16 + l16] = f2bf(v);
        }
      }
    }
  }
}

// ---------------- depthwise conv k=3 along sequence + exact GELU, bf16 ----------
__global__ __launch_bounds__(256) void dwconv_kernel(
    const ushort* __restrict__ u, const float* __restrict__ w,
    const float* __restrict__ bia, ushort* __restrict__ out)
{
  int g = blockIdx.x * 256 + threadIdx.x;   // 8 channels per thread
  int row = g >> 8;
  int c8 = (g & 255) * 8;
  int n = row & (HH - 1);
  size_t base = (size_t)row * HIDD + c8;
  uint4 z4; z4.x = z4.y = z4.z = z4.w = 0;
  uint4 u1 = *(const uint4*)(u + base);
  uint4 u0 = (n > 0)      ? *(const uint4*)(u + base - HIDD) : z4;
  uint4 u2 = (n < HH - 1) ? *(const uint4*)(u + base + HIDD) : z4;
  const ushort* p0 = (const ushort*)&u0;
  const ushort* p1 = (const ushort*)&u1;
  const ushort* p2 = (const ushort*)&u2;
  union { ushort h[8]; uint4 v; } o;
  #pragma unroll
  for (int k = 0; k < 8; k++){
    int c = c8 + k;
    float acc = bia[c] + w[c * 3] * bf2f(p0[k]) + w[c * 3 + 1] * bf2f(p1[k]) + w[c * 3 + 2] * bf2f(p2[k]);
    o.h[k] = f2bf(gelu_f(acc));
  }
  *(uint4*)(out + base) = o.v;
}

// ---------------- launch ----------------
extern "C" void kernel_launch(void* const* d_in, const int* in_sizes, int n_in,
                              void* d_out, int out_size, void* d_ws, size_t ws_size,
                              hipStream_t stream)
{
  const float* x      = (const float*)d_in[0];
  const float* ln1w   = (const float*)d_in[1];
  const float* ln1b   = (const float*)d_in[2];
  const float* ln2w   = (const float*)d_in[3];
  const float* ln2b   = (const float*)d_in[4];
  const float* q_b    = (const float*)d_in[6];
  const float* kv_b   = (const float*)d_in[8];
  const float* proj_b = (const float*)d_in[10];
  const float* fc1_b  = (const float*)d_in[12];
  const float* dw_w   = (const float*)d_in[13];
  const float* dw_b   = (const float*)d_in[14];
  const float* fc2_b  = (const float*)d_in[16];
  const float* px1_b  = (const float*)d_in[18];
  const float* px2_b  = (const float*)d_in[20];
  const float* gamma1 = (const float*)d_in[21];
  const float* gamma2 = (const float*)d_in[22];
  float* out = (float*)d_out;

  char* ws = (char*)d_ws;
  ushort* wbf = (ushort*)(ws);               //  8,388,608 B  weights bf16
  ushort* lnb = (ushort*)(ws + 8388608);     //  8,519,680 B  ln out
  ushort* qb  = (ushort*)(ws + 16908288);    //  8,519,680 B  Q (pre-scaled)
  ushort* kb  = (ushort*)(ws + 25427968);    //  8,519,680 B  K
  ushort* vtb = (ushort*)(ws + 33947648);    //  8,519,680 B  V^T (bh,d,n)
  ushort* ab  = (ushort*)(ws + 42467328);    //  8,519,680 B  attention out
  // overlay region: opart+ml used by attn/combine, then f1/dg by FFN
  ushort* opart = (ushort*)(ws + 50987008);  // 25,952,256 B (bf16 partials)
  float*  mlb   = (float*)(ws + 76939264);   //    811,008 B
  ushort* f1  = (ushort*)(ws + 50987008);    // 33,554,432 B
  ushort* dg  = (ushort*)(ws + 84541440);    // 33,554,432 B
  ushort* sm1 = (ushort*)(ws + 118095872);   //    262,144 B

  ushort* wq    = wbf;              // also covers wkv at +262144 (fused O=1536)
  ushort* wproj = wbf + 786432;
  ushort* wfc1  = wbf + 1048576;
  ushort* wfc2  = wbf + 2097152;
  ushort* wpx1  = wbf + 3145728;
  ushort* wpx2  = wbf + 3670016;

  wconv_kernel<<<4096, 256, 0, stream>>>((const float*)d_in[5], (const float*)d_in[7],
                                         (const float*)d_in[9], (const float*)d_in[11],
                                         (const float*)d_in[15], (const float*)d_in[17],
                                         (const float*)d_in[19], wbf);
  ln_kernel<<<2080, 256, 0, stream>>>(x, ln1w, ln1b, lnb);
  // fused QKV: O = 1536 (q_w ++ kv_w are adjacent in wbf)
  gemm_kernel<128,0,0,3><<<dim3(65, 12), 256, 0, stream>>>(
      lnb, 512, wq, q_b, kv_b, qb, kb, nullptr, nullptr, nullptr, vtb, 512, 1536);
  attn_kernel<<<dim3(33, 8, 3), 256, 0, stream>>>(qb, kb, vtb, opart, mlb);
  attn_combine_kernel<<<dim3(33, 8), 256, 0, stream>>>(opart, mlb, ab);
  gemm_kernel<64,0,0,2><<<dim3(65, 8), 256, 0, stream>>>(
      ab, 512, wproj, proj_b, nullptr, nullptr, nullptr, out, x, gamma1, nullptr, 512, 512);
  ln_kernel<<<2080, 256, 0, stream>>>(out, ln2w, ln2b, lnb);
  gemm_kernel<128,1,0,0><<<dim3(64, 16), 256, 0, stream>>>(
      lnb, 512, wfc1, fc1_b, nullptr, f1, nullptr, nullptr, nullptr, nullptr, nullptr, 512, 2048);
  dwconv_kernel<<<8192, 256, 0, stream>>>(f1, dw_w, dw_b, dg);
  gemm_kernel<64,0,1,2><<<dim3(64, 8), 256, 0, stream>>>(
      dg, 2048, wfc2, fc2_b, nullptr, nullptr, nullptr, out, out, gamma2, nullptr, 2048, 512);
  gemm_kernel<64,2,0,1><<<dim3(1, 16), 256, 0, stream>>>(
      lnb, 512, wpx1, px1_b, nullptr, sm1, nullptr, nullptr, nullptr, nullptr, nullptr, 512, 1024);
  gemm_kernel<64,0,2,2><<<dim3(1, 8), 256, 0, stream>>>(
      sm1, 1024, wpx2, px2_b, nullptr, nullptr, nullptr, out, out, gamma2, nullptr, 1024, 512);
}

// Round 5
// 600.276 us; speedup vs baseline: 1.6184x; 1.6184x over previous
//
#include <hip/hip_runtime.h>
#include <stdint.h>

#define BB 2
#define NN 4160
#define CC 512
#define HIDD 2048
#define HH 4096
#define QSCALE 0.12751742f   // log2(e)/sqrt(128), folded into Q epilogue

typedef short bf16x8 __attribute__((ext_vector_type(8)));
typedef float f32x4 __attribute__((ext_vector_type(4)));

__device__ __forceinline__ float bf2f(ushort u){
  union { uint32_t u32; float f; } c; c.u32 = ((uint32_t)u) << 16; return c.f;
}
__device__ __forceinline__ ushort f2bf(float f){
  union { float f; uint32_t u32; } c; c.f = f;
  uint32_t r = c.u32 + 0x7fffu + ((c.u32 >> 16) & 1u);
  return (ushort)(r >> 16);
}
__device__ __forceinline__ float gelu_f(float x){
  return 0.5f * x * (1.0f + erff(x * 0.70710678118654752440f));
}
// async global->LDS, 16B per lane; lds ptr must be wave-uniform-base + lane*16
__device__ __forceinline__ void async16(ushort* lds, const ushort* g){
  __builtin_amdgcn_global_load_lds(
      (const __attribute__((address_space(1))) uint32_t*)g,
      (__attribute__((address_space(3))) uint32_t*)lds, 16, 0, 0);
}

template<int MODE>
__device__ __forceinline__ int rowmap(int m){
  if (MODE == 0) return m;                              // identity
  if (MODE == 1) return (m >> 12) * NN + (m & 4095);    // seq rows (H=4096)
  return (m >> 6) * NN + HH + (m & 63);                 // sem rows (64/batch)
}

// ---------------- weights fp32 -> bf16 (one contiguous bf16 arena) ----------------
__global__ __launch_bounds__(256) void wconv_kernel(
    const float* __restrict__ s0, const float* __restrict__ s1,
    const float* __restrict__ s2, const float* __restrict__ s3,
    const float* __restrict__ s4, const float* __restrict__ s5,
    const float* __restrict__ s6, ushort* __restrict__ dst)
{
  int i4 = (blockIdx.x * 256 + threadIdx.x) * 4;
  const float* s; int off;
  if      (i4 <  262144){ s = s0; off = 0;       }
  else if (i4 <  786432){ s = s1; off = 262144;  }
  else if (i4 < 1048576){ s = s2; off = 786432;  }
  else if (i4 < 2097152){ s = s3; off = 1048576; }
  else if (i4 < 3145728){ s = s4; off = 2097152; }
  else if (i4 < 3670016){ s = s5; off = 3145728; }
  else                  { s = s6; off = 3670016; }
  float4 v = *(const float4*)(s + (i4 - off));
  union { ushort h[4]; uint2 u; } o;
  o.h[0] = f2bf(v.x); o.h[1] = f2bf(v.y); o.h[2] = f2bf(v.z); o.h[3] = f2bf(v.w);
  *(uint2*)(dst + i4) = o.u;
}

// ---------------- LayerNorm over C=512, one wave per row, bf16 out ----------------
__global__ __launch_bounds__(256) void ln_kernel(
    const float* __restrict__ x, const float* __restrict__ w,
    const float* __restrict__ b, ushort* __restrict__ out)
{
  int row  = blockIdx.x * 4 + (threadIdx.x >> 6);
  int lane = threadIdx.x & 63;
  const float4* xr = (const float4*)(x + (size_t)row * CC);
  float4 v0 = xr[lane];
  float4 v1 = xr[lane + 64];
  float s  = v0.x + v0.y + v0.z + v0.w + v1.x + v1.y + v1.z + v1.w;
  float ss = v0.x*v0.x + v0.y*v0.y + v0.z*v0.z + v0.w*v0.w
           + v1.x*v1.x + v1.y*v1.y + v1.z*v1.z + v1.w*v1.w;
  #pragma unroll
  for (int off = 1; off < 64; off <<= 1){
    s  += __shfl_xor(s, off);
    ss += __shfl_xor(ss, off);
  }
  float mu  = s * (1.0f / CC);
  float var = ss * (1.0f / CC) - mu * mu;
  float rs  = rsqrtf(var + 1e-5f);
  const float4* wp = (const float4*)w;
  const float4* bp = (const float4*)b;
  float4 w0 = wp[lane], w1 = wp[lane + 64], b0 = bp[lane], b1 = bp[lane + 64];
  union { ushort h[4]; uint2 u; } o0, o1;
  o0.h[0] = f2bf((v0.x - mu) * rs * w0.x + b0.x);
  o0.h[1] = f2bf((v0.y - mu) * rs * w0.y + b0.y);
  o0.h[2] = f2bf((v0.z - mu) * rs * w0.z + b0.z);
  o0.h[3] = f2bf((v0.w - mu) * rs * w0.w + b0.w);
  o1.h[0] = f2bf((v1.x - mu) * rs * w1.x + b1.x);
  o1.h[1] = f2bf((v1.y - mu) * rs * w1.y + b1.y);
  o1.h[2] = f2bf((v1.z - mu) * rs * w1.z + b1.z);
  o1.h[3] = f2bf((v1.w - mu) * rs * w1.w + b1.w);
  ushort* orow = out + (size_t)row * CC;
  ((uint2*)orow)[lane]      = o0.u;
  ((uint2*)orow)[lane + 64] = o1.u;
}

// ---------------- GEMM: out = A(MxK) @ W(OxK)^T + bias; BM=128, BK=64 ------------
// (round-3 verified version: global_load_lds staging, swizzled LDS)
// EPI 0: bf16 store   EPI 1: bf16(gelu)   EPI 2: outf = resid + gamma*(acc+bias)
// EPI 3: fused QKV: col<512 -> qb*QSCALE; col<1024 -> kb; else -> vt transposed
template<int BN, int AMAP, int OMAP, int EPI>
__global__ __launch_bounds__(256) void gemm_kernel(
    const ushort* __restrict__ A, int lda,
    const ushort* __restrict__ W,
    const float* __restrict__ bias, const float* __restrict__ bias2,
    ushort* __restrict__ outb, ushort* __restrict__ outb2,
    float* __restrict__ outf,
    const float* __restrict__ resid, const float* __restrict__ gamma,
    ushort* __restrict__ vt, int K, int O)
{
  constexpr int NCT = BN / 32;           // col 16-tiles per wave
  __shared__ __align__(16) ushort As[128 * 64];
  __shared__ __align__(16) ushort Ws[BN * 64];
  int tid  = threadIdx.x;
  int lane = tid & 63;
  int wv   = tid >> 6;
  int w0   = wv & 1, w1 = wv >> 1;
  int quad = lane >> 4, l16 = lane & 15;
  int m0 = blockIdx.x * 128;
  int o0 = blockIdx.y * BN;

  f32x4 acc[4][NCT];
  f32x4 zf = {0.f, 0.f, 0.f, 0.f};
  #pragma unroll
  for (int i = 0; i < 4; i++)
    #pragma unroll
    for (int j = 0; j < NCT; j++) acc[i][j] = zf;

  for (int k0 = 0; k0 < K; k0 += 64){
    __syncthreads();   // previous tile's ds_reads done before overwrite
    #pragma unroll
    for (int i = 0; i < 4; i++){
      int o = i * 256 + tid;
      int row = o >> 3, c = (o & 7) ^ (row & 7);
      int gm = rowmap<AMAP>(m0 + row);
      async16(&As[o * 8], A + (size_t)gm * lda + k0 + c * 8);
    }
    #pragma unroll
    for (int i = 0; i < BN * 8 / 256; i++){
      int o = i * 256 + tid;
      int row = o >> 3, c = (o & 7) ^ (row & 7);
      async16(&Ws[o * 8], W + (size_t)(o0 + row) * K + k0 + c * 8);
    }
    __syncthreads();   // drain global_load_lds
    #pragma unroll
    for (int kk = 0; kk < 2; kk++){
      bf16x8 af[4], bfr[NCT];
      #pragma unroll
      for (int rt = 0; rt < 4; rt++){
        int row = w1 * 64 + rt * 16 + l16;
        af[rt] = *(const bf16x8*)&As[(row * 8 + ((kk * 4 + quad) ^ (row & 7))) * 8];
      }
      #pragma unroll
      for (int ct = 0; ct < NCT; ct++){
        int row = w0 * (BN / 2) + ct * 16 + l16;
        bfr[ct] = *(const bf16x8*)&Ws[(row * 8 + ((kk * 4 + quad) ^ (row & 7))) * 8];
      }
      #pragma unroll
      for (int rt = 0; rt < 4; rt++)
        #pragma unroll
        for (int ct = 0; ct < NCT; ct++)
          acc[rt][ct] = __builtin_amdgcn_mfma_f32_16x16x32_bf16(af[rt], bfr[ct], acc[rt][ct], 0, 0, 0);
    }
  }

  #pragma unroll
  for (int ct = 0; ct < NCT; ct++){
    int col = o0 + w0 * (BN / 2) + ct * 16 + l16;
    #pragma unroll
    for (int rt = 0; rt < 4; rt++){
      int mb = m0 + w1 * 64 + rt * 16 + quad * 4;
      if (EPI == 3){
        if (col < 512){
          float bs = bias[col];
          #pragma unroll
          for (int r = 0; r < 4; r++)
            outb[(size_t)(mb + r) * 512 + col] = f2bf((acc[rt][ct][r] + bs) * QSCALE);
        } else if (col < 1024){
          float bs = bias2[col - 512];
          #pragma unroll
          for (int r = 0; r < 4; r++)
            outb2[(size_t)(mb + r) * 512 + (col - 512)] = f2bf(acc[rt][ct][r] + bs);
        } else {
          float bs = bias2[col - 512];
          int dd = col - 1024;
          int h2 = dd >> 7, d = dd & 127;
          int bbat = (mb >= NN) ? 1 : 0;
          int n = mb - bbat * NN;
          union { ushort h[4]; uint2 u; } pk;
          #pragma unroll
          for (int r = 0; r < 4; r++) pk.h[r] = f2bf(acc[rt][ct][r] + bs);
          *(uint2*)&vt[((size_t)((bbat * 4 + h2) * 128 + d)) * NN + n] = pk.u;
        }
      } else {
        float bs = bias[col];
        #pragma unroll
        for (int r = 0; r < 4; r++){
          float v = acc[rt][ct][r] + bs;
          if (EPI == 1) v = gelu_f(v);
          if (EPI == 0 || EPI == 1){
            outb[(size_t)rowmap<OMAP>(mb + r) * O + col] = f2bf(v);
          } else {
            size_t off = (size_t)rowmap<OMAP>(mb + r) * O + col;
            outf[off] = resid[off] + gamma[col] * v;
          }
        }
      }
    }
  }
}

// ---------------- flash attention, split-K partials --------------------------------
// (round-3 verified structure: K/V register-prefetch one tile ahead, LDS staged)
// Q tile 128 (4 waves x 32 rows), key tile 64, 3 key-splits. Q pre-scaled ->
// exp2-domain softmax. Partials stored as PACKED bf16, fully coalesced
// (round-4 verified format) -> ~11x less write traffic than fp32 scalar.
__global__ __launch_bounds__(256, 2) void attn_kernel(
    const ushort* __restrict__ q, const ushort* __restrict__ kbuf,
    const ushort* __restrict__ vt, ushort* __restrict__ opart, float* __restrict__ ml)
{
  __shared__ __align__(16) ushort Ks[64 * 128];    // [row][c16^(row&7)]
  __shared__ __align__(16) ushort VTs[128 * 64];   // [d][c8^(d&7)]
  __shared__ __align__(16) ushort Ps[128 * 64];    // [row][col ^ quad*16]
  int tid = threadIdx.x, lane = tid & 63, wv = tid >> 6;
  int quad = lane >> 4, l16 = lane & 15;
  int qt = blockIdx.x, bh = blockIdx.y, ks = blockIdx.z;
  int b = bh >> 2, h = bh & 3;
  int jt0 = ks * 22;
  int jt1 = (ks == 2) ? 65 : jt0 + 22;

  // Q fragments straight from global (A-layout: lane=row, quad=k-chunk)
  bf16x8 qf[2][4];
  #pragma unroll
  for (int rt = 0; rt < 2; rt++)
    #pragma unroll
    for (int kb = 0; kb < 4; kb++){
      int qr = qt * 128 + wv * 32 + rt * 16 + l16;
      qr = (qr < NN) ? qr : (NN - 1);
      qf[rt][kb] = *(const bf16x8*)(q + ((size_t)(b * NN + qr)) * CC + h * 128 + kb * 32 + quad * 8);
    }

  float mrow[2][4], lrow[2][4];
  #pragma unroll
  for (int rt = 0; rt < 2; rt++)
    #pragma unroll
    for (int r = 0; r < 4; r++){ mrow[rt][r] = -1e30f; lrow[rt][r] = 0.f; }
  f32x4 oa[2][8];
  f32x4 zf = {0.f, 0.f, 0.f, 0.f};
  #pragma unroll
  for (int rt = 0; rt < 2; rt++)
    #pragma unroll
    for (int nb = 0; nb < 8; nb++) oa[rt][nb] = zf;

  const ushort* kg0 = kbuf + ((size_t)b * NN) * CC + h * 128;
  const ushort* vg0 = vt + ((size_t)bh * 128) * NN;

  uint4 kreg[4], vreg[4];
  // prologue: load first tile into registers
  {
    const ushort* kgb = kg0 + (size_t)(jt0 * 64) * CC;
    const ushort* vgb = vg0 + jt0 * 64;
    #pragma unroll
    for (int i = 0; i < 4; i++){
      int o = i * 256 + tid;
      kreg[i] = *(const uint4*)(kgb + (size_t)(o >> 4) * CC + (o & 15) * 8);
      vreg[i] = *(const uint4*)(vgb + (size_t)(o >> 3) * NN + (o & 7) * 8);
    }
  }

  for (int jt = jt0; jt < jt1; jt++){
    __syncthreads();   // all waves done reading Ks/VTs from previous compute
    // registers -> LDS (swizzled)
    #pragma unroll
    for (int i = 0; i < 4; i++){
      int o = i * 256 + tid;
      int row = o >> 4, ck = (o & 15) ^ (row & 7);
      *(uint4*)&Ks[(row * 16 + ck) * 8] = kreg[i];
      int d = o >> 3, cv = (o & 7) ^ (d & 7);
      *(uint4*)&VTs[(d * 8 + cv) * 8] = vreg[i];
    }
    // issue next tile's loads (in flight across the whole compute phase)
    if (jt + 1 < jt1){
      const ushort* kgb = kg0 + (size_t)((jt + 1) * 64) * CC;
      const ushort* vgb = vg0 + (jt + 1) * 64;
      #pragma unroll
      for (int i = 0; i < 4; i++){
        int o = i * 256 + tid;
        kreg[i] = *(const uint4*)(kgb + (size_t)(o >> 4) * CC + (o & 15) * 8);
        vreg[i] = *(const uint4*)(vgb + (size_t)(o >> 3) * NN + (o & 7) * 8);
      }
    }
    __syncthreads();   // staged tile visible

    // S = Q K^T : K fragment shared across both row-tiles
    f32x4 s[2][4];
    #pragma unroll
    for (int rt = 0; rt < 2; rt++)
      #pragma unroll
      for (int ct = 0; ct < 4; ct++) s[rt][ct] = zf;
    #pragma unroll
    for (int ct = 0; ct < 4; ct++)
      #pragma unroll
      for (int kb = 0; kb < 4; kb++){
        int row = ct * 16 + l16;
        bf16x8 kf = *(const bf16x8*)&Ks[(row * 16 + ((kb * 4 + quad) ^ (l16 & 7))) * 8];
        #pragma unroll
        for (int rt = 0; rt < 2; rt++)
          s[rt][ct] = __builtin_amdgcn_mfma_f32_16x16x32_bf16(qf[rt][kb], kf, s[rt][ct], 0, 0, 0);
      }

    // online softmax (exp2 domain), rows quad*4+r per rt
    #pragma unroll
    for (int rt = 0; rt < 2; rt++){
      #pragma unroll
      for (int r = 0; r < 4; r++){
        float mx = fmaxf(fmaxf(s[rt][0][r], s[rt][1][r]), fmaxf(s[rt][2][r], s[rt][3][r]));
        #pragma unroll
        for (int off = 1; off < 16; off <<= 1) mx = fmaxf(mx, __shfl_xor(mx, off));
        float mn = fmaxf(mrow[rt][r], mx);
        float al = __builtin_amdgcn_exp2f(mrow[rt][r] - mn);
        mrow[rt][r] = mn;
        #pragma unroll
        for (int ct = 0; ct < 4; ct++) s[rt][ct][r] = __builtin_amdgcn_exp2f(s[rt][ct][r] - mn);
        float t = s[rt][0][r] + s[rt][1][r] + s[rt][2][r] + s[rt][3][r];
        #pragma unroll
        for (int off = 1; off < 16; off <<= 1) t += __shfl_xor(t, off);
        lrow[rt][r] = lrow[rt][r] * al + t;
        #pragma unroll
        for (int nb = 0; nb < 8; nb++) oa[rt][nb][r] *= al;
      }
      // P: C-layout -> LDS (swizzled by quad), wave-private rows
      #pragma unroll
      for (int ct = 0; ct < 4; ct++)
        #pragma unroll
        for (int r = 0; r < 4; r++)
          Ps[(wv * 32 + rt * 16 + quad * 4 + r) * 64 + ((ct * 16 + l16) ^ (quad * 16))] = f2bf(s[rt][ct][r]);
    }

    // O += P V
    #pragma unroll
    for (int kb2 = 0; kb2 < 2; kb2++){
      bf16x8 pf[2];
      #pragma unroll
      for (int rt = 0; rt < 2; rt++){
        int rowA = wv * 32 + rt * 16 + l16;
        pf[rt] = *(const bf16x8*)&Ps[rowA * 64 + ((kb2 * 32 + quad * 8) ^ ((((l16 >> 2) & 3)) * 16))];
      }
      #pragma unroll
      for (int nb = 0; nb < 8; nb++){
        int d = nb * 16 + l16;
        bf16x8 vf = *(const bf16x8*)&VTs[(d * 8 + ((kb2 * 4 + quad) ^ (l16 & 7))) * 8];
        #pragma unroll
        for (int rt = 0; rt < 2; rt++)
          oa[rt][nb] = __builtin_amdgcn_mfma_f32_16x16x32_bf16(pf[rt], vf, oa[rt][nb], 0, 0, 0);
      }
    }
  }

  // bf16 partials, fully coalesced (round-4 verified layout):
  // element (row,col): row=wv*32+rt*16+quad*4+r, col=nb*16+l16
  //   -> opart[part*16384 + ((wv*2+rt)*8+nb)*256 + lane*4 + r]
  int part = (qt * 8 + bh) * 3 + ks;
  ushort* op = opart + (size_t)part * 16384;
  #pragma unroll
  for (int rt = 0; rt < 2; rt++)
    #pragma unroll
    for (int nb = 0; nb < 8; nb++){
      union { ushort h[4]; uint2 u; } pk;
      #pragma unroll
      for (int r = 0; r < 4; r++) pk.h[r] = f2bf(oa[rt][nb][r]);
      *(uint2*)&op[(((wv * 2 + rt) * 8 + nb) * 64 + lane) * 4] = pk.u;
    }
  if (l16 == 0){
    #pragma unroll
    for (int rt = 0; rt < 2; rt++)
      #pragma unroll
      for (int r = 0; r < 4; r++){
        int row = wv * 32 + rt * 16 + quad * 4 + r;
        ml[(size_t)part * 256 + row]       = mrow[rt][r];
        ml[(size_t)part * 256 + 128 + row] = lrow[rt][r];
      }
  }
}

// ---------------- combine 3 key-split bf16 partials -> bf16 attention out --------
__global__ __launch_bounds__(256) void attn_combine_kernel(
    const ushort* __restrict__ opart, const float* __restrict__ ml,
    ushort* __restrict__ out)
{
  int qt = blockIdx.x, bh = blockIdx.y;
  int b = bh >> 2, h = bh & 3;
  int tid = threadIdx.x;
  int lane = tid & 63, quad = lane >> 4, l16 = lane & 15;
  int base = (qt * 8 + bh) * 3;
  const ushort* p0 = opart + (size_t)(base + 0) * 16384;
  const ushort* p1 = opart + (size_t)(base + 1) * 16384;
  const ushort* p2 = opart + (size_t)(base + 2) * 16384;

  #pragma unroll
  for (int pass = 0; pass < 2; pass++){
    int wvrt = (tid >> 6) * 2 + pass;           // (wv*2+rt) in [0,8)
    int wv = wvrt >> 1, rt = wvrt & 1;
    float w0r[4], w1r[4], w2r[4], invr[4];
    int rows[4];
    #pragma unroll
    for (int r = 0; r < 4; r++){
      int row = wv * 32 + rt * 16 + quad * 4 + r;
      rows[r] = row;
      float m0 = ml[(size_t)(base + 0) * 256 + row];
      float m1 = ml[(size_t)(base + 1) * 256 + row];
      float m2 = ml[(size_t)(base + 2) * 256 + row];
      float l0 = ml[(size_t)(base + 0) * 256 + 128 + row];
      float l1 = ml[(size_t)(base + 1) * 256 + 128 + row];
      float l2 = ml[(size_t)(base + 2) * 256 + 128 + row];
      float mx = fmaxf(fmaxf(m0, m1), m2);
      w0r[r] = __builtin_amdgcn_exp2f(m0 - mx);
      w1r[r] = __builtin_amdgcn_exp2f(m1 - mx);
      w2r[r] = __builtin_amdgcn_exp2f(m2 - mx);
      invr[r] = 1.0f / (w0r[r] * l0 + w1r[r] * l1 + w2r[r] * l2);
    }
    #pragma unroll
    for (int nb = 0; nb < 8; nb++){
      int idx = ((wvrt * 8 + nb) * 64 + lane) * 4;
      union { ushort h[4]; uint2 u; } a, c, d;
      a.u = *(const uint2*)&p0[idx];
      c.u = *(const uint2*)&p1[idx];
      d.u = *(const uint2*)&p2[idx];
      #pragma unroll
      for (int r = 0; r < 4; r++){
        int n = qt * 128 + rows[r];
        if (n < NN){
          float v = (w0r[r] * bf2f(a.h[r]) + w1r[r] * bf2f(c.h[r]) + w2r[r] * bf2f(d.h[r])) * invr[r];
          out[((size_t)(b * NN + n)) * CC + h * 128 + nb * 16 + l16] = f2bf(v);
        }
      }
    }
  }
}

// ---------------- depthwise conv k=3 along sequence + exact GELU, bf16 ----------
__global__ __launch_bounds__(256) void dwconv_kernel(
    const ushort* __restrict__ u, const float* __restrict__ w,
    const float* __restrict__ bia, ushort* __restrict__ out)
{
  int g = blockIdx.x * 256 + threadIdx.x;   // 8 channels per thread
  int row = g >> 8;
  int c8 = (g & 255) * 8;
  int n = row & (HH - 1);
  size_t base = (size_t)row * HIDD + c8;
  uint4 z4; z4.x = z4.y = z4.z = z4.w = 0;
  uint4 u1 = *(const uint4*)(u + base);
  uint4 u0 = (n > 0)      ? *(const uint4*)(u + base - HIDD) : z4;
  uint4 u2 = (n < HH - 1) ? *(const uint4*)(u + base + HIDD) : z4;
  const ushort* p0 = (const ushort*)&u0;
  const ushort* p1 = (const ushort*)&u1;
  const ushort* p2 = (const ushort*)&u2;
  union { ushort h[8]; uint4 v; } o;
  #pragma unroll
  for (int k = 0; k < 8; k++){
    int c = c8 + k;
    float acc = bia[c] + w[c * 3] * bf2f(p0[k]) + w[c * 3 + 1] * bf2f(p1[k]) + w[c * 3 + 2] * bf2f(p2[k]);
    o.h[k] = f2bf(gelu_f(acc));
  }
  *(uint4*)(out + base) = o.v;
}

// ---------------- launch ----------------
extern "C" void kernel_launch(void* const* d_in, const int* in_sizes, int n_in,
                              void* d_out, int out_size, void* d_ws, size_t ws_size,
                              hipStream_t stream)
{
  const float* x      = (const float*)d_in[0];
  const float* ln1w   = (const float*)d_in[1];
  const float* ln1b   = (const float*)d_in[2];
  const float* ln2w   = (const float*)d_in[3];
  const float* ln2b   = (const float*)d_in[4];
  const float* q_b    = (const float*)d_in[6];
  const float* kv_b   = (const float*)d_in[8];
  const float* proj_b = (const float*)d_in[10];
  const float* fc1_b  = (const float*)d_in[12];
  const float* dw_w   = (const float*)d_in[13];
  const float* dw_b   = (const float*)d_in[14];
  const float* fc2_b  = (const float*)d_in[16];
  const float* px1_b  = (const float*)d_in[18];
  const float* px2_b  = (const float*)d_in[20];
  const float* gamma1 = (const float*)d_in[21];
  const float* gamma2 = (const float*)d_in[22];
  float* out = (float*)d_out;

  char* ws = (char*)d_ws;
  ushort* wbf = (ushort*)(ws);               //  8,388,608 B  weights bf16
  ushort* lnb = (ushort*)(ws + 8388608);     //  8,519,680 B  ln out
  ushort* qb  = (ushort*)(ws + 16908288);    //  8,519,680 B  Q (pre-scaled)
  ushort* kb  = (ushort*)(ws + 25427968);    //  8,519,680 B  K
  ushort* vtb = (ushort*)(ws + 33947648);    //  8,519,680 B  V^T (bh,d,n)
  ushort* ab  = (ushort*)(ws + 42467328);    //  8,519,680 B  attention out
  // overlay region: opart+ml used by attn/combine, then f1/dg by FFN
  ushort* opart = (ushort*)(ws + 50987008);  // 25,952,256 B (bf16 partials)
  float*  mlb   = (float*)(ws + 76939264);   //    811,008 B
  ushort* f1  = (ushort*)(ws + 50987008);    // 33,554,432 B
  ushort* dg  = (ushort*)(ws + 84541440);    // 33,554,432 B
  ushort* sm1 = (ushort*)(ws + 118095872);   //    262,144 B

  ushort* wq    = wbf;              // also covers wkv at +262144 (fused O=1536)
  ushort* wproj = wbf + 786432;
  ushort* wfc1  = wbf + 1048576;
  ushort* wfc2  = wbf + 2097152;
  ushort* wpx1  = wbf + 3145728;
  ushort* wpx2  = wbf + 3670016;

  wconv_kernel<<<4096, 256, 0, stream>>>((const float*)d_in[5], (const float*)d_in[7],
                                         (const float*)d_in[9], (const float*)d_in[11],
                                         (const float*)d_in[15], (const float*)d_in[17],
                                         (const float*)d_in[19], wbf);
  ln_kernel<<<2080, 256, 0, stream>>>(x, ln1w, ln1b, lnb);
  // fused QKV: O = 1536 (q_w ++ kv_w are adjacent in wbf)
  gemm_kernel<128,0,0,3><<<dim3(65, 12), 256, 0, stream>>>(
      lnb, 512, wq, q_b, kv_b, qb, kb, nullptr, nullptr, nullptr, vtb, 512, 1536);
  attn_kernel<<<dim3(33, 8, 3), 256, 0, stream>>>(qb, kb, vtb, opart, mlb);
  attn_combine_kernel<<<dim3(33, 8), 256, 0, stream>>>(opart, mlb, ab);
  gemm_kernel<64,0,0,2><<<dim3(65, 8), 256, 0, stream>>>(
      ab, 512, wproj, proj_b, nullptr, nullptr, nullptr, out, x, gamma1, nullptr, 512, 512);
  ln_kernel<<<2080, 256, 0, stream>>>(out, ln2w, ln2b, lnb);
  gemm_kernel<128,1,0,0><<<dim3(64, 16), 256, 0, stream>>>(
      lnb, 512, wfc1, fc1_b, nullptr, f1, nullptr, nullptr, nullptr, nullptr, nullptr, 512, 2048);
  dwconv_kernel<<<8192, 256, 0, stream>>>(f1, dw_w, dw_b, dg);
  gemm_kernel<64,0,1,2><<<dim3(64, 8), 256, 0, stream>>>(
      dg, 2048, wfc2, fc2_b, nullptr, nullptr, nullptr, out, out, gamma2, nullptr, 2048, 512);
  gemm_kernel<64,2,0,1><<<dim3(1, 16), 256, 0, stream>>>(
      lnb, 512, wpx1, px1_b, nullptr, sm1, nullptr, nullptr, nullptr, nullptr, nullptr, 512, 1024);
  gemm_kernel<64,0,2,2><<<dim3(1, 8), 256, 0, stream>>>(
      sm1, 1024, wpx2, px2_b, nullptr, nullptr, nullptr, out, out, gamma2, nullptr, 1024, 512);
}

// Round 10
// 598.371 us; speedup vs baseline: 1.6236x; 1.0032x over previous
//
#include <hip/hip_runtime.h>
#include <stdint.h>

#define BB 2
#define NN 4160
#define CC 512
#define HIDD 2048
#define HH 4096
#define QSCALE 0.12751742f   // log2(e)/sqrt(128), folded into Q epilogue

typedef short bf16x8 __attribute__((ext_vector_type(8)));
typedef float f32x4 __attribute__((ext_vector_type(4)));

__device__ __forceinline__ float bf2f(ushort u){
  union { uint32_t u32; float f; } c; c.u32 = ((uint32_t)u) << 16; return c.f;
}
__device__ __forceinline__ ushort f2bf(float f){
  union { float f; uint32_t u32; } c; c.f = f;
  uint32_t r = c.u32 + 0x7fffu + ((c.u32 >> 16) & 1u);
  return (ushort)(r >> 16);
}
__device__ __forceinline__ float gelu_f(float x){
  return 0.5f * x * (1.0f + erff(x * 0.70710678118654752440f));
}
// async global->LDS, 16B per lane; lds ptr must be wave-uniform-base + lane*16
__device__ __forceinline__ void async16(ushort* lds, const ushort* g){
  __builtin_amdgcn_global_load_lds(
      (const __attribute__((address_space(1))) uint32_t*)g,
      (__attribute__((address_space(3))) uint32_t*)lds, 16, 0, 0);
}

template<int MODE>
__device__ __forceinline__ int rowmap(int m){
  if (MODE == 0) return m;                              // identity
  if (MODE == 1) return (m >> 12) * NN + (m & 4095);    // seq rows (H=4096)
  return (m >> 6) * NN + HH + (m & 63);                 // sem rows (64/batch)
}

// ---------------- weights fp32 -> bf16 (one contiguous bf16 arena) ----------------
__global__ __launch_bounds__(256) void wconv_kernel(
    const float* __restrict__ s0, const float* __restrict__ s1,
    const float* __restrict__ s2, const float* __restrict__ s3,
    const float* __restrict__ s4, const float* __restrict__ s5,
    const float* __restrict__ s6, ushort* __restrict__ dst)
{
  int i4 = (blockIdx.x * 256 + threadIdx.x) * 4;
  const float* s; int off;
  if      (i4 <  262144){ s = s0; off = 0;       }
  else if (i4 <  786432){ s = s1; off = 262144;  }
  else if (i4 < 1048576){ s = s2; off = 786432;  }
  else if (i4 < 2097152){ s = s3; off = 1048576; }
  else if (i4 < 3145728){ s = s4; off = 2097152; }
  else if (i4 < 3670016){ s = s5; off = 3145728; }
  else                  { s = s6; off = 3670016; }
  float4 v = *(const float4*)(s + (i4 - off));
  union { ushort h[4]; uint2 u; } o;
  o.h[0] = f2bf(v.x); o.h[1] = f2bf(v.y); o.h[2] = f2bf(v.z); o.h[3] = f2bf(v.w);
  *(uint2*)(dst + i4) = o.u;
}

// ---------------- LayerNorm over C=512, one wave per row, bf16 out ----------------
__global__ __launch_bounds__(256) void ln_kernel(
    const float* __restrict__ x, const float* __restrict__ w,
    const float* __restrict__ b, ushort* __restrict__ out)
{
  int row  = blockIdx.x * 4 + (threadIdx.x >> 6);
  int lane = threadIdx.x & 63;
  const float4* xr = (const float4*)(x + (size_t)row * CC);
  float4 v0 = xr[lane];
  float4 v1 = xr[lane + 64];
  float s  = v0.x + v0.y + v0.z + v0.w + v1.x + v1.y + v1.z + v1.w;
  float ss = v0.x*v0.x + v0.y*v0.y + v0.z*v0.z + v0.w*v0.w
           + v1.x*v1.x + v1.y*v1.y + v1.z*v1.z + v1.w*v1.w;
  #pragma unroll
  for (int off = 1; off < 64; off <<= 1){
    s  += __shfl_xor(s, off);
    ss += __shfl_xor(ss, off);
  }
  float mu  = s * (1.0f / CC);
  float var = ss * (1.0f / CC) - mu * mu;
  float rs  = rsqrtf(var + 1e-5f);
  const float4* wp = (const float4*)w;
  const float4* bp = (const float4*)b;
  float4 w0 = wp[lane], w1 = wp[lane + 64], b0 = bp[lane], b1 = bp[lane + 64];
  union { ushort h[4]; uint2 u; } o0, o1;
  o0.h[0] = f2bf((v0.x - mu) * rs * w0.x + b0.x);
  o0.h[1] = f2bf((v0.y - mu) * rs * w0.y + b0.y);
  o0.h[2] = f2bf((v0.z - mu) * rs * w0.z + b0.z);
  o0.h[3] = f2bf((v0.w - mu) * rs * w0.w + b0.w);
  o1.h[0] = f2bf((v1.x - mu) * rs * w1.x + b1.x);
  o1.h[1] = f2bf((v1.y - mu) * rs * w1.y + b1.y);
  o1.h[2] = f2bf((v1.z - mu) * rs * w1.z + b1.z);
  o1.h[3] = f2bf((v1.w - mu) * rs * w1.w + b1.w);
  ushort* orow = out + (size_t)row * CC;
  ((uint2*)orow)[lane]      = o0.u;
  ((uint2*)orow)[lane + 64] = o1.u;
}

// ---------------- GEMM: out = A(MxK) @ W(OxK)^T + bias; BM=128, BK=64 ------------
// (round-3 verified version: global_load_lds staging, swizzled LDS)
// EPI 0: bf16 store   EPI 1: bf16(gelu)   EPI 2: outf = resid + gamma*(acc+bias)
// EPI 3: fused QKV: col<512 -> qb*QSCALE; col<1024 -> kb; else -> vt transposed
template<int BN, int AMAP, int OMAP, int EPI>
__global__ __launch_bounds__(256) void gemm_kernel(
    const ushort* __restrict__ A, int lda,
    const ushort* __restrict__ W,
    const float* __restrict__ bias, const float* __restrict__ bias2,
    ushort* __restrict__ outb, ushort* __restrict__ outb2,
    float* __restrict__ outf,
    const float* __restrict__ resid, const float* __restrict__ gamma,
    ushort* __restrict__ vt, int K, int O)
{
  constexpr int NCT = BN / 32;           // col 16-tiles per wave
  __shared__ __align__(16) ushort As[128 * 64];
  __shared__ __align__(16) ushort Ws[BN * 64];
  int tid  = threadIdx.x;
  int lane = tid & 63;
  int wv   = tid >> 6;
  int w0   = wv & 1, w1 = wv >> 1;
  int quad = lane >> 4, l16 = lane & 15;
  int m0 = blockIdx.x * 128;
  int o0 = blockIdx.y * BN;

  f32x4 acc[4][NCT];
  f32x4 zf = {0.f, 0.f, 0.f, 0.f};
  #pragma unroll
  for (int i = 0; i < 4; i++)
    #pragma unroll
    for (int j = 0; j < NCT; j++) acc[i][j] = zf;

  for (int k0 = 0; k0 < K; k0 += 64){
    __syncthreads();   // previous tile's ds_reads done before overwrite
    #pragma unroll
    for (int i = 0; i < 4; i++){
      int o = i * 256 + tid;
      int row = o >> 3, c = (o & 7) ^ (row & 7);
      int gm = rowmap<AMAP>(m0 + row);
      async16(&As[o * 8], A + (size_t)gm * lda + k0 + c * 8);
    }
    #pragma unroll
    for (int i = 0; i < BN * 8 / 256; i++){
      int o = i * 256 + tid;
      int row = o >> 3, c = (o & 7) ^ (row & 7);
      async16(&Ws[o * 8], W + (size_t)(o0 + row) * K + k0 + c * 8);
    }
    __syncthreads();   // drain global_load_lds
    #pragma unroll
    for (int kk = 0; kk < 2; kk++){
      bf16x8 af[4], bfr[NCT];
      #pragma unroll
      for (int rt = 0; rt < 4; rt++){
        int row = w1 * 64 + rt * 16 + l16;
        af[rt] = *(const bf16x8*)&As[(row * 8 + ((kk * 4 + quad) ^ (row & 7))) * 8];
      }
      #pragma unroll
      for (int ct = 0; ct < NCT; ct++){
        int row = w0 * (BN / 2) + ct * 16 + l16;
        bfr[ct] = *(const bf16x8*)&Ws[(row * 8 + ((kk * 4 + quad) ^ (row & 7))) * 8];
      }
      #pragma unroll
      for (int rt = 0; rt < 4; rt++)
        #pragma unroll
        for (int ct = 0; ct < NCT; ct++)
          acc[rt][ct] = __builtin_amdgcn_mfma_f32_16x16x32_bf16(af[rt], bfr[ct], acc[rt][ct], 0, 0, 0);
    }
  }

  #pragma unroll
  for (int ct = 0; ct < NCT; ct++){
    int col = o0 + w0 * (BN / 2) + ct * 16 + l16;
    #pragma unroll
    for (int rt = 0; rt < 4; rt++){
      int mb = m0 + w1 * 64 + rt * 16 + quad * 4;
      if (EPI == 3){
        if (col < 512){
          float bs = bias[col];
          #pragma unroll
          for (int r = 0; r < 4; r++)
            outb[(size_t)(mb + r) * 512 + col] = f2bf((acc[rt][ct][r] + bs) * QSCALE);
        } else if (col < 1024){
          float bs = bias2[col - 512];
          #pragma unroll
          for (int r = 0; r < 4; r++)
            outb2[(size_t)(mb + r) * 512 + (col - 512)] = f2bf(acc[rt][ct][r] + bs);
        } else {
          float bs = bias2[col - 512];
          int dd = col - 1024;
          int h2 = dd >> 7, d = dd & 127;
          int bbat = (mb >= NN) ? 1 : 0;
          int n = mb - bbat * NN;
          union { ushort h[4]; uint2 u; } pk;
          #pragma unroll
          for (int r = 0; r < 4; r++) pk.h[r] = f2bf(acc[rt][ct][r] + bs);
          *(uint2*)&vt[((size_t)((bbat * 4 + h2) * 128 + d)) * NN + n] = pk.u;
        }
      } else {
        float bs = bias[col];
        #pragma unroll
        for (int r = 0; r < 4; r++){
          float v = acc[rt][ct][r] + bs;
          if (EPI == 1) v = gelu_f(v);
          if (EPI == 0 || EPI == 1){
            outb[(size_t)rowmap<OMAP>(mb + r) * O + col] = f2bf(v);
          } else {
            size_t off = (size_t)rowmap<OMAP>(mb + r) * O + col;
            outf[off] = resid[off] + gamma[col] * v;
          }
        }
      }
    }
  }
}

// ---------------- flash attention, split-K partials --------------------------------
// (round-3 verified structure: K/V register-prefetch one tile ahead, LDS staged)
// Q tile 128 (4 waves x 32 rows), key tile 64, 3 key-splits. Q pre-scaled ->
// exp2-domain softmax. Partials stored as PACKED bf16, fully coalesced
// (round-4 verified format) -> ~11x less write traffic than fp32 scalar.
__global__ __launch_bounds__(256, 2) void attn_kernel(
    const ushort* __restrict__ q, const ushort* __restrict__ kbuf,
    const ushort* __restrict__ vt, ushort* __restrict__ opart, float* __restrict__ ml)
{
  __shared__ __align__(16) ushort Ks[64 * 128];    // [row][c16^(row&7)]
  __shared__ __align__(16) ushort VTs[128 * 64];   // [d][c8^(d&7)]
  __shared__ __align__(16) ushort Ps[128 * 64];    // [row][col ^ quad*16]
  int tid = threadIdx.x, lane = tid & 63, wv = tid >> 6;
  int quad = lane >> 4, l16 = lane & 15;
  int qt = blockIdx.x, bh = blockIdx.y, ks = blockIdx.z;
  int b = bh >> 2, h = bh & 3;
  int jt0 = ks * 22;
  int jt1 = (ks == 2) ? 65 : jt0 + 22;

  // Q fragments straight from global (A-layout: lane=row, quad=k-chunk)
  bf16x8 qf[2][4];
  #pragma unroll
  for (int rt = 0; rt < 2; rt++)
    #pragma unroll
    for (int kb = 0; kb < 4; kb++){
      int qr = qt * 128 + wv * 32 + rt * 16 + l16;
      qr = (qr < NN) ? qr : (NN - 1);
      qf[rt][kb] = *(const bf16x8*)(q + ((size_t)(b * NN + qr)) * CC + h * 128 + kb * 32 + quad * 8);
    }

  float mrow[2][4], lrow[2][4];
  #pragma unroll
  for (int rt = 0; rt < 2; rt++)
    #pragma unroll
    for (int r = 0; r < 4; r++){ mrow[rt][r] = -1e30f; lrow[rt][r] = 0.f; }
  f32x4 oa[2][8];
  f32x4 zf = {0.f, 0.f, 0.f, 0.f};
  #pragma unroll
  for (int rt = 0; rt < 2; rt++)
    #pragma unroll
    for (int nb = 0; nb < 8; nb++) oa[rt][nb] = zf;

  const ushort* kg0 = kbuf + ((size_t)b * NN) * CC + h * 128;
  const ushort* vg0 = vt + ((size_t)bh * 128) * NN;

  uint4 kreg[4], vreg[4];
  // prologue: load first tile into registers
  {
    const ushort* kgb = kg0 + (size_t)(jt0 * 64) * CC;
    const ushort* vgb = vg0 + jt0 * 64;
    #pragma unroll
    for (int i = 0; i < 4; i++){
      int o = i * 256 + tid;
      kreg[i] = *(const uint4*)(kgb + (size_t)(o >> 4) * CC + (o & 15) * 8);
      vreg[i] = *(const uint4*)(vgb + (size_t)(o >> 3) * NN + (o & 7) * 8);
    }
  }

  for (int jt = jt0; jt < jt1; jt++){
    __syncthreads();   // all waves done reading Ks/VTs from previous compute
    // registers -> LDS (swizzled)
    #pragma unroll
    for (int i = 0; i < 4; i++){
      int o = i * 256 + tid;
      int row = o >> 4, ck = (o & 15) ^ (row & 7);
      *(uint4*)&Ks[(row * 16 + ck) * 8] = kreg[i];
      int d = o >> 3, cv = (o & 7) ^ (d & 7);
      *(uint4*)&VTs[(d * 8 + cv) * 8] = vreg[i];
    }
    // issue next tile's loads (in flight across the whole compute phase)
    if (jt + 1 < jt1){
      const ushort* kgb = kg0 + (size_t)((jt + 1) * 64) * CC;
      const ushort* vgb = vg0 + (jt + 1) * 64;
      #pragma unroll
      for (int i = 0; i < 4; i++){
        int o = i * 256 + tid;
        kreg[i] = *(const uint4*)(kgb + (size_t)(o >> 4) * CC + (o & 15) * 8);
        vreg[i] = *(const uint4*)(vgb + (size_t)(o >> 3) * NN + (o & 7) * 8);
      }
    }
    __syncthreads();   // staged tile visible

    // S = Q K^T : K fragment shared across both row-tiles
    f32x4 s[2][4];
    #pragma unroll
    for (int rt = 0; rt < 2; rt++)
      #pragma unroll
      for (int ct = 0; ct < 4; ct++) s[rt][ct] = zf;
    #pragma unroll
    for (int ct = 0; ct < 4; ct++)
      #pragma unroll
      for (int kb = 0; kb < 4; kb++){
        int row = ct * 16 + l16;
        bf16x8 kf = *(const bf16x8*)&Ks[(row * 16 + ((kb * 4 + quad) ^ (l16 & 7))) * 8];
        #pragma unroll
        for (int rt = 0; rt < 2; rt++)
          s[rt][ct] = __builtin_amdgcn_mfma_f32_16x16x32_bf16(qf[rt][kb], kf, s[rt][ct], 0, 0, 0);
      }

    // online softmax (exp2 domain), rows quad*4+r per rt
    #pragma unroll
    for (int rt = 0; rt < 2; rt++){
      #pragma unroll
      for (int r = 0; r < 4; r++){
        float mx = fmaxf(fmaxf(s[rt][0][r], s[rt][1][r]), fmaxf(s[rt][2][r], s[rt][3][r]));
        #pragma unroll
        for (int off = 1; off < 16; off <<= 1) mx = fmaxf(mx, __shfl_xor(mx, off));
        float mn = fmaxf(mrow[rt][r], mx);
        float al = __builtin_amdgcn_exp2f(mrow[rt][r] - mn);
        mrow[rt][r] = mn;
        #pragma unroll
        for (int ct = 0; ct < 4; ct++) s[rt][ct][r] = __builtin_amdgcn_exp2f(s[rt][ct][r] - mn);
        float t = s[rt][0][r] + s[rt][1][r] + s[rt][2][r] + s[rt][3][r];
        #pragma unroll
        for (int off = 1; off < 16; off <<= 1) t += __shfl_xor(t, off);
        lrow[rt][r] = lrow[rt][r] * al + t;
        #pragma unroll
        for (int nb = 0; nb < 8; nb++) oa[rt][nb][r] *= al;
      }
      // P: C-layout -> LDS (swizzled by quad), wave-private rows
      #pragma unroll
      for (int ct = 0; ct < 4; ct++)
        #pragma unroll
        for (int r = 0; r < 4; r++)
          Ps[(wv * 32 + rt * 16 + quad * 4 + r) * 64 + ((ct * 16 + l16) ^ (quad * 16))] = f2bf(s[rt][ct][r]);
    }

    // O += P V
    #pragma unroll
    for (int kb2 = 0; kb2 < 2; kb2++){
      bf16x8 pf[2];
      #pragma unroll
      for (int rt = 0; rt < 2; rt++){
        int rowA = wv * 32 + rt * 16 + l16;
        pf[rt] = *(const bf16x8*)&Ps[rowA * 64 + ((kb2 * 32 + quad * 8) ^ ((((l16 >> 2) & 3)) * 16))];
      }
      #pragma unroll
      for (int nb = 0; nb < 8; nb++){
        int d = nb * 16 + l16;
        bf16x8 vf = *(const bf16x8*)&VTs[(d * 8 + ((kb2 * 4 + quad) ^ (l16 & 7))) * 8];
        #pragma unroll
        for (int rt = 0; rt < 2; rt++)
          oa[rt][nb] = __builtin_amdgcn_mfma_f32_16x16x32_bf16(pf[rt], vf, oa[rt][nb], 0, 0, 0);
      }
    }
  }

  // bf16 partials, fully coalesced (round-4 verified layout):
  // element (row,col): row=wv*32+rt*16+quad*4+r, col=nb*16+l16
  //   -> opart[part*16384 + ((wv*2+rt)*8+nb)*256 + lane*4 + r]
  int part = (qt * 8 + bh) * 3 + ks;
  ushort* op = opart + (size_t)part * 16384;
  #pragma unroll
  for (int rt = 0; rt < 2; rt++)
    #pragma unroll
    for (int nb = 0; nb < 8; nb++){
      union { ushort h[4]; uint2 u; } pk;
      #pragma unroll
      for (int r = 0; r < 4; r++) pk.h[r] = f2bf(oa[rt][nb][r]);
      *(uint2*)&op[(((wv * 2 + rt) * 8 + nb) * 64 + lane) * 4] = pk.u;
    }
  if (l16 == 0){
    #pragma unroll
    for (int rt = 0; rt < 2; rt++)
      #pragma unroll
      for (int r = 0; r < 4; r++){
        int row = wv * 32 + rt * 16 + quad * 4 + r;
        ml[(size_t)part * 256 + row]       = mrow[rt][r];
        ml[(size_t)part * 256 + 128 + row] = lrow[rt][r];
      }
  }
}

// ---------------- combine 3 key-split bf16 partials -> bf16 attention out --------
__global__ __launch_bounds__(256) void attn_combine_kernel(
    const ushort* __restrict__ opart, const float* __restrict__ ml,
    ushort* __restrict__ out)
{
  int qt = blockIdx.x, bh = blockIdx.y;
  int b = bh >> 2, h = bh & 3;
  int tid = threadIdx.x;
  int lane = tid & 63, quad = lane >> 4, l16 = lane & 15;
  int base = (qt * 8 + bh) * 3;
  const ushort* p0 = opart + (size_t)(base + 0) * 16384;
  const ushort* p1 = opart + (size_t)(base + 1) * 16384;
  const ushort* p2 = opart + (size_t)(base + 2) * 16384;

  #pragma unroll
  for (int pass = 0; pass < 2; pass++){
    int wvrt = (tid >> 6) * 2 + pass;           // (wv*2+rt) in [0,8)
    int wv = wvrt >> 1, rt = wvrt & 1;
    float w0r[4], w1r[4], w2r[4], invr[4];
    int rows[4];
    #pragma unroll
    for (int r = 0; r < 4; r++){
      int row = wv * 32 + rt * 16 + quad * 4 + r;
      rows[r] = row;
      float m0 = ml[(size_t)(base + 0) * 256 + row];
      float m1 = ml[(size_t)(base + 1) * 256 + row];
      float m2 = ml[(size_t)(base + 2) * 256 + row];
      float l0 = ml[(size_t)(base + 0) * 256 + 128 + row];
      float l1 = ml[(size_t)(base + 1) * 256 + 128 + row];
      float l2 = ml[(size_t)(base + 2) * 256 + 128 + row];
      float mx = fmaxf(fmaxf(m0, m1), m2);
      w0r[r] = __builtin_amdgcn_exp2f(m0 - mx);
      w1r[r] = __builtin_amdgcn_exp2f(m1 - mx);
      w2r[r] = __builtin_amdgcn_exp2f(m2 - mx);
      invr[r] = 1.0f / (w0r[r] * l0 + w1r[r] * l1 + w2r[r] * l2);
    }
    #pragma unroll
    for (int nb = 0; nb < 8; nb++){
      int idx = ((wvrt * 8 + nb) * 64 + lane) * 4;
      union { ushort h[4]; uint2 u; } a, c, d;
      a.u = *(const uint2*)&p0[idx];
      c.u = *(const uint2*)&p1[idx];
      d.u = *(const uint2*)&p2[idx];
      #pragma unroll
      for (int r = 0; r < 4; r++){
        int n = qt * 128 + rows[r];
        if (n < NN){
          float v = (w0r[r] * bf2f(a.h[r]) + w1r[r] * bf2f(c.h[r]) + w2r[r] * bf2f(d.h[r])) * invr[r];
          out[((size_t)(b * NN + n)) * CC + h * 128 + nb * 16 + l16] = f2bf(v);
        }
      }
    }
  }
}

// ---------------- depthwise conv k=3 along sequence + exact GELU, bf16 ----------
__global__ __launch_bounds__(256) void dwconv_kernel(
    const ushort* __restrict__ u, const float* __restrict__ w,
    const float* __restrict__ bia, ushort* __restrict__ out)
{
  int g = blockIdx.x * 256 + threadIdx.x;   // 8 channels per thread
  int row = g >> 8;
  int c8 = (g & 255) * 8;
  int n = row & (HH - 1);
  size_t base = (size_t)row * HIDD + c8;
  uint4 z4; z4.x = z4.y = z4.z = z4.w = 0;
  uint4 u1 = *(const uint4*)(u + base);
  uint4 u0 = (n > 0)      ? *(const uint4*)(u + base - HIDD) : z4;
  uint4 u2 = (n < HH - 1) ? *(const uint4*)(u + base + HIDD) : z4;
  const ushort* p0 = (const ushort*)&u0;
  const ushort* p1 = (const ushort*)&u1;
  const ushort* p2 = (const ushort*)&u2;
  union { ushort h[8]; uint4 v; } o;
  #pragma unroll
  for (int k = 0; k < 8; k++){
    int c = c8 + k;
    float acc = bia[c] + w[c * 3] * bf2f(p0[k]) + w[c * 3 + 1] * bf2f(p1[k]) + w[c * 3 + 2] * bf2f(p2[k]);
    o.h[k] = f2bf(gelu_f(acc));
  }
  *(uint4*)(out + base) = o.v;
}

// ---------------- launch ----------------
extern "C" void kernel_launch(void* const* d_in, const int* in_sizes, int n_in,
                              void* d_out, int out_size, void* d_ws, size_t ws_size,
                              hipStream_t stream)
{
  const float* x      = (const float*)d_in[0];
  const float* ln1w   = (const float*)d_in[1];
  const float* ln1b   = (const float*)d_in[2];
  const float* ln2w   = (const float*)d_in[3];
  const float* ln2b   = (const float*)d_in[4];
  const float* q_b    = (const float*)d_in[6];
  const float* kv_b   = (const float*)d_in[8];
  const float* proj_b = (const float*)d_in[10];
  const float* fc1_b  = (const float*)d_in[12];
  const float* dw_w   = (const float*)d_in[13];
  const float* dw_b   = (const float*)d_in[14];
  const float* fc2_b  = (const float*)d_in[16];
  const float* px1_b  = (const float*)d_in[18];
  const float* px2_b  = (const float*)d_in[20];
  const float* gamma1 = (const float*)d_in[21];
  const float* gamma2 = (const float*)d_in[22];
  float* out = (float*)d_out;

  char* ws = (char*)d_ws;
  ushort* wbf = (ushort*)(ws);               //  8,388,608 B  weights bf16
  ushort* lnb = (ushort*)(ws + 8388608);     //  8,519,680 B  ln out
  ushort* qb  = (ushort*)(ws + 16908288);    //  8,519,680 B  Q (pre-scaled)
  ushort* kb  = (ushort*)(ws + 25427968);    //  8,519,680 B  K
  ushort* vtb = (ushort*)(ws + 33947648);    //  8,519,680 B  V^T (bh,d,n)
  ushort* ab  = (ushort*)(ws + 42467328);    //  8,519,680 B  attention out
  // overlay region: opart+ml used by attn/combine, then f1/dg by FFN
  ushort* opart = (ushort*)(ws + 50987008);  // 25,952,256 B (bf16 partials)
  float*  mlb   = (float*)(ws + 76939264);   //    811,008 B
  ushort* f1  = (ushort*)(ws + 50987008);    // 33,554,432 B
  ushort* dg  = (ushort*)(ws + 84541440);    // 33,554,432 B
  ushort* sm1 = (ushort*)(ws + 118095872);   //    262,144 B

  ushort* wq    = wbf;              // also covers wkv at +262144 (fused O=1536)
  ushort* wproj = wbf + 786432;
  ushort* wfc1  = wbf + 1048576;
  ushort* wfc2  = wbf + 2097152;
  ushort* wpx1  = wbf + 3145728;
  ushort* wpx2  = wbf + 3670016;

  wconv_kernel<<<4096, 256, 0, stream>>>((const float*)d_in[5], (const float*)d_in[7],
                                         (const float*)d_in[9], (const float*)d_in[11],
                                         (const float*)d_in[15], (const float*)d_in[17],
                                         (const float*)d_in[19], wbf);
  ln_kernel<<<2080, 256, 0, stream>>>(x, ln1w, ln1b, lnb);
  // fused QKV: O = 1536 (q_w ++ kv_w are adjacent in wbf)
  gemm_kernel<128,0,0,3><<<dim3(65, 12), 256, 0, stream>>>(
      lnb, 512, wq, q_b, kv_b, qb, kb, nullptr, nullptr, nullptr, vtb, 512, 1536);
  attn_kernel<<<dim3(33, 8, 3), 256, 0, stream>>>(qb, kb, vtb, opart, mlb);
  attn_combine_kernel<<<dim3(33, 8), 256, 0, stream>>>(opart, mlb, ab);
  gemm_kernel<64,0,0,2><<<dim3(65, 8), 256, 0, stream>>>(
      ab, 512, wproj, proj_b, nullptr, nullptr, nullptr, out, x, gamma1, nullptr, 512, 512);
  ln_kernel<<<2080, 256, 0, stream>>>(out, ln2w, ln2b, lnb);
  gemm_kernel<128,1,0,0><<<dim3(64, 16), 256, 0, stream>>>(
      lnb, 512, wfc1, fc1_b, nullptr, f1, nullptr, nullptr, nullptr, nullptr, nullptr, 512, 2048);
  dwconv_kernel<<<8192, 256, 0, stream>>>(f1, dw_w, dw_b, dg);
  gemm_kernel<64,0,1,2><<<dim3(64, 8), 256, 0, stream>>>(
      dg, 2048, wfc2, fc2_b, nullptr, nullptr, nullptr, out, out, gamma2, nullptr, 2048, 512);
  gemm_kernel<64,2,0,1><<<dim3(1, 16), 256, 0, stream>>>(
      lnb, 512, wpx1, px1_b, nullptr, sm1, nullptr, nullptr, nullptr, nullptr, nullptr, 512, 1024);
  gemm_kernel<64,0,2,2><<<dim3(1, 8), 256, 0, stream>>>(
      sm1, 1024, wpx2, px2_b, nullptr, nullptr, nullptr, out, out, gamma2, nullptr, 1024, 512);
}